// Round 1
// baseline (791.041 us; speedup 1.0000x reference)
//
#include <hip/hip_runtime.h>
#include <hip/hip_bf16.h>

#define B_ 8
#define L_ 1024
#define H_ 8
#define E_ 64
#define SCALE 0.125f

// ---------------------------------------------------------------------------
// prior_association kernel: one block per (b, i) row.
// prior[b,i,s] = sum_h exp(-|i-s|/sigma[b,h,s]) / rownorm  (the 1/H cancels)
// ---------------------------------------------------------------------------
__global__ __launch_bounds__(256) void prior_kernel(const float* __restrict__ sigma,
                                                    float* __restrict__ outP) {
    const int bx = blockIdx.x;          // b*L + i
    const int b  = bx >> 10;
    const int i  = bx & 1023;
    const int t  = threadIdx.x;

    __shared__ float rowbuf[L_];
    __shared__ float wred[4];
    __shared__ float sinv;

    const float* sb = sigma + (size_t)b * H_ * L_;
    float part = 0.f;
    for (int s = t; s < L_; s += 256) {
        int di = i - s; di = di < 0 ? -di : di;
        const float dn = -1.4426950408889634f * (float)di;  // -|i-s| * log2(e)
        float acc = 0.f;
#pragma unroll
        for (int h = 0; h < H_; ++h) {
            const float sg = sb[h * L_ + s];
            acc += exp2f(dn * __builtin_amdgcn_rcpf(sg));
        }
        rowbuf[s] = acc;
        part += acc;
    }
#pragma unroll
    for (int off = 1; off < 64; off <<= 1) part += __shfl_xor(part, off);
    if ((t & 63) == 0) wred[t >> 6] = part;
    __syncthreads();
    if (t == 0) sinv = 1.f / (wred[0] + wred[1] + wred[2] + wred[3]);
    __syncthreads();
    const float inv = sinv;
    float* op = outP + (size_t)bx * L_;
    for (int s = t; s < L_; s += 256) op[s] = rowbuf[s] * inv;
}

// ---------------------------------------------------------------------------
// attention kernel: one block per (b, h, row-tile of 8 rows). 256 threads.
// Phase 1: QK^T + exp (no max-subtract; logits bounded ~|6|).  Each thread
//          owns one column per 256-col tile, K row reused across 8 rows,
//          Q reads are wave-uniform (scalar loads).
// Phase 2: row-sum reduce -> 1/sum.
// Phase 3: write normalized series (+ explicit zeros above the causal edge).
// Phase 4: PV from LDS-transposed e; coalesced float2 V loads; LDS reduce.
// ---------------------------------------------------------------------------
__global__ __launch_bounds__(256) void attn_kernel(const float* __restrict__ Q,
                                                   const float* __restrict__ K,
                                                   const float* __restrict__ V,
                                                   float* __restrict__ outV,
                                                   float* __restrict__ outS) {
    const int bx = blockIdx.x;
    const int it = bx & 127;          // row-tile index
    const int bh = bx >> 7;           // b*8 + h
    const int b  = bh >> 3;
    const int h  = bh & 7;
    const int i0 = it << 3;
    const int t  = threadIdx.x;
    const int nct  = (i0 + 8 + 255) >> 8;   // 1..4 col-tiles of 256
    const int cend = nct << 8;

    __shared__ float4 et0[L_];              // e for rows 0..3, col-major
    __shared__ float4 et1[L_];              // e for rows 4..7
    __shared__ float  wsum[4][8];
    __shared__ float  sinv[8];
    __shared__ float  red2[8][8][32][2];    // [g][r][p][j]

    const float* Qb = Q + ((size_t)(b * L_ + i0) * H_ + h) * E_;
    const float* Kb = K + ((size_t)b * L_ * H_ + h) * E_;
    const float* Vb = V + ((size_t)b * L_ * H_ + h) * E_;

    float sum_p[8];
#pragma unroll
    for (int r = 0; r < 8; ++r) sum_p[r] = 0.f;
    float e_keep[4][8];

    // ---- Phase 1: scores -> e ----
#pragma unroll
    for (int ct = 0; ct < 4; ++ct) {
        if (ct >= nct) continue;            // uniform per block
        const int s = (ct << 8) + t;
        float acc[8];
#pragma unroll
        for (int r = 0; r < 8; ++r) acc[r] = 0.f;
        const float4* kp = (const float4*)(Kb + (size_t)s * H_ * E_);
#pragma unroll
        for (int e4 = 0; e4 < 16; ++e4) {
            const float4 k4 = kp[e4];
#pragma unroll
            for (int r = 0; r < 8; ++r) {
                const float4 q4 = *(const float4*)(Qb + (size_t)r * H_ * E_ + (e4 << 2));
                acc[r] = fmaf(q4.x, k4.x, acc[r]);
                acc[r] = fmaf(q4.y, k4.y, acc[r]);
                acc[r] = fmaf(q4.z, k4.z, acc[r]);
                acc[r] = fmaf(q4.w, k4.w, acc[r]);
            }
        }
#pragma unroll
        for (int r = 0; r < 8; ++r) {
            const float ev = (s <= i0 + r) ? __expf(SCALE * acc[r]) : 0.f;
            sum_p[r] += ev;
            e_keep[ct][r] = ev;
        }
        et0[s] = make_float4(e_keep[ct][0], e_keep[ct][1], e_keep[ct][2], e_keep[ct][3]);
        et1[s] = make_float4(e_keep[ct][4], e_keep[ct][5], e_keep[ct][6], e_keep[ct][7]);
    }

    // ---- Phase 2: row sums ----
#pragma unroll
    for (int r = 0; r < 8; ++r) {
        float v = sum_p[r];
#pragma unroll
        for (int off = 1; off < 64; off <<= 1) v += __shfl_xor(v, off);
        sum_p[r] = v;
    }
    if ((t & 63) == 0) {
#pragma unroll
        for (int r = 0; r < 8; ++r) wsum[t >> 6][r] = sum_p[r];
    }
    __syncthreads();
    if (t < 8) sinv[t] = 1.f / (wsum[0][t] + wsum[1][t] + wsum[2][t] + wsum[3][t]);
    __syncthreads();
    float inv[8];
#pragma unroll
    for (int r = 0; r < 8; ++r) inv[r] = sinv[r];

    // ---- Phase 3: write series ----
    float* Sb = outS + ((size_t)bh * L_ + i0) * L_;
#pragma unroll
    for (int ct = 0; ct < 4; ++ct) {
        if (ct >= nct) continue;
        const int s = (ct << 8) + t;
#pragma unroll
        for (int r = 0; r < 8; ++r) Sb[(size_t)r * L_ + s] = e_keep[ct][r] * inv[r];
    }
    for (int s = cend + t; s < L_; s += 256) {
#pragma unroll
        for (int r = 0; r < 8; ++r) Sb[(size_t)r * L_ + s] = 0.f;
    }

    // ---- Phase 4: PV ----
    const int p  = t & 31;
    const int g  = t >> 5;
    const int d0 = p << 1;
    float va[8], vb[8];
#pragma unroll
    for (int r = 0; r < 8; ++r) { va[r] = 0.f; vb[r] = 0.f; }
    for (int s = g; s < cend; s += 8) {
        const float2 v2 = *(const float2*)(Vb + (size_t)s * H_ * E_ + d0);
        const float4 e0 = et0[s];
        const float4 e1 = et1[s];
        va[0] = fmaf(e0.x, v2.x, va[0]); vb[0] = fmaf(e0.x, v2.y, vb[0]);
        va[1] = fmaf(e0.y, v2.x, va[1]); vb[1] = fmaf(e0.y, v2.y, vb[1]);
        va[2] = fmaf(e0.z, v2.x, va[2]); vb[2] = fmaf(e0.z, v2.y, vb[2]);
        va[3] = fmaf(e0.w, v2.x, va[3]); vb[3] = fmaf(e0.w, v2.y, vb[3]);
        va[4] = fmaf(e1.x, v2.x, va[4]); vb[4] = fmaf(e1.x, v2.y, vb[4]);
        va[5] = fmaf(e1.y, v2.x, va[5]); vb[5] = fmaf(e1.y, v2.y, vb[5]);
        va[6] = fmaf(e1.z, v2.x, va[6]); vb[6] = fmaf(e1.z, v2.y, vb[6]);
        va[7] = fmaf(e1.w, v2.x, va[7]); vb[7] = fmaf(e1.w, v2.y, vb[7]);
    }
#pragma unroll
    for (int r = 0; r < 8; ++r) { red2[g][r][p][0] = va[r]; red2[g][r][p][1] = vb[r]; }
    __syncthreads();
    {
        const int rr = t >> 5;
        const int pp = t & 31;
        float a0 = 0.f, a1 = 0.f;
#pragma unroll
        for (int gg = 0; gg < 8; ++gg) { a0 += red2[gg][rr][pp][0]; a1 += red2[gg][rr][pp][1]; }
        const float iv = sinv[rr];
        float2 o; o.x = a0 * iv; o.y = a1 * iv;
        *(float2*)(outV + ((size_t)(b * L_ + i0 + rr) * H_ + h) * E_ + (pp << 1)) = o;
    }
}

extern "C" void kernel_launch(void* const* d_in, const int* in_sizes, int n_in,
                              void* d_out, int out_size, void* d_ws, size_t ws_size,
                              hipStream_t stream) {
    const float* Q     = (const float*)d_in[0];
    const float* K     = (const float*)d_in[1];
    const float* V     = (const float*)d_in[2];
    const float* sigma = (const float*)d_in[3];

    float* out  = (float*)d_out;
    float* outV = out;                                    // (B,L,H,D)   4,194,304
    float* outS = out + (size_t)B_ * L_ * H_ * E_;        // (B,H,L,S)  67,108,864
    float* outP = outS + (size_t)B_ * H_ * L_ * L_;       // (B,L,S)     8,388,608

    attn_kernel<<<dim3(B_ * H_ * (L_ / 8)), dim3(256), 0, stream>>>(Q, K, V, outV, outS);
    prior_kernel<<<dim3(B_ * L_), dim3(256), 0, stream>>>(sigma, outP);
}

// Round 3
// 631.684 us; speedup vs baseline: 1.2523x; 1.2523x over previous
//
#include <hip/hip_runtime.h>
#include <hip/hip_bf16.h>

#define B_ 8
#define L_ 1024
#define H_ 8
#define E_ 64
#define HE 512
#define SCALE 0.125f

// ---------------------------------------------------------------------------
// K transpose: KT[b,h,e,l] = K[b,l,h,e].  1024 blocks x 256 thr.
// ---------------------------------------------------------------------------
__global__ __launch_bounds__(256) void ktrans_kernel(const float* __restrict__ K,
                                                     float* __restrict__ KT) {
    const int bx = blockIdx.x;
    const int bh = bx >> 4;            // b*H + h
    const int l0 = (bx & 15) << 6;
    const int b = bh >> 3, h = bh & 7;
    const int t = threadIdx.x;
    __shared__ float lds[64][65];

    const int r = t >> 2, c = t & 3;   // 4 threads per row, 16 floats each
    const float* src = K + ((size_t)(b * L_ + l0 + r) * H_ + h) * E_ + (c << 4);
#pragma unroll
    for (int j = 0; j < 4; ++j) {
        const float4 v = *(const float4*)(src + (j << 2));
        const int e = (c << 4) + (j << 2);
        lds[r][e + 0] = v.x; lds[r][e + 1] = v.y; lds[r][e + 2] = v.z; lds[r][e + 3] = v.w;
    }
    __syncthreads();
    const int l = t & 63, e0 = (t >> 6) << 4;
    float* dst = KT + (size_t)bh * E_ * L_ + l0 + l;
#pragma unroll
    for (int k = 0; k < 16; ++k) dst[(size_t)(e0 + k) * L_] = lds[l][e0 + k];
}

// ---------------------------------------------------------------------------
// prior: 2048 blocks (b, 4-row group) x 256 thr, each thread owns 4 cols.
// All-register; native rcp/exp2.
// ---------------------------------------------------------------------------
__global__ __launch_bounds__(256) void prior_kernel(const float* __restrict__ sigma,
                                                    float* __restrict__ outP) {
    const int bx = blockIdx.x;
    const int b  = bx >> 8;
    const int i0 = (bx & 255) << 2;
    const int t  = threadIdx.x;
    const int s0 = t << 2;

    __shared__ float wred[4][4];
    __shared__ float sinv[4];

    const float* sb = sigma + (size_t)b * H_ * L_;
    float wv[8][4];
#pragma unroll
    for (int h = 0; h < 8; ++h) {
        const float4 sg = *(const float4*)(sb + h * L_ + s0);
        wv[h][0] = -1.4426950408889634f * __builtin_amdgcn_rcpf(sg.x);
        wv[h][1] = -1.4426950408889634f * __builtin_amdgcn_rcpf(sg.y);
        wv[h][2] = -1.4426950408889634f * __builtin_amdgcn_rcpf(sg.z);
        wv[h][3] = -1.4426950408889634f * __builtin_amdgcn_rcpf(sg.w);
    }
    float dist[4][4];
#pragma unroll
    for (int row = 0; row < 4; ++row)
#pragma unroll
        for (int j = 0; j < 4; ++j) {
            int di = (i0 + row) - (s0 + j);
            dist[row][j] = (float)(di < 0 ? -di : di);
        }
    float acc[4][4];
#pragma unroll
    for (int row = 0; row < 4; ++row)
#pragma unroll
        for (int j = 0; j < 4; ++j) acc[row][j] = 0.f;
#pragma unroll
    for (int h = 0; h < 8; ++h)
#pragma unroll
        for (int row = 0; row < 4; ++row)
#pragma unroll
            for (int j = 0; j < 4; ++j)
                acc[row][j] += __builtin_amdgcn_exp2f(dist[row][j] * wv[h][j]);

    float tsum[4];
#pragma unroll
    for (int row = 0; row < 4; ++row) {
        float v = acc[row][0] + acc[row][1] + acc[row][2] + acc[row][3];
#pragma unroll
        for (int off = 1; off < 64; off <<= 1) v += __shfl_xor(v, off);
        tsum[row] = v;
    }
    if ((t & 63) == 0) {
#pragma unroll
        for (int row = 0; row < 4; ++row) wred[t >> 6][row] = tsum[row];
    }
    __syncthreads();
    if (t < 4) sinv[t] = 1.f / (wred[0][t] + wred[1][t] + wred[2][t] + wred[3][t]);
    __syncthreads();
#pragma unroll
    for (int row = 0; row < 4; ++row) {
        const float iv = sinv[row];
        float4 o;
        o.x = acc[row][0] * iv; o.y = acc[row][1] * iv;
        o.z = acc[row][2] * iv; o.w = acc[row][3] * iv;
        *(float4*)(outP + (size_t)(b * L_ + i0 + row) * L_ + s0) = o;
    }
}

// ---------------------------------------------------------------------------
// attention: 8192 blocks (b,h,row-tile of 8) x 256 thr.
// Phase 1: coalesced KT dword loads, wave-uniform scalar Q, exp -> e (regs+LDS)
// Phase 4: thread=(s-group, d-quad), float4 V loads, e broadcast from LDS.
// ---------------------------------------------------------------------------
__global__ __launch_bounds__(256) void attn_kernel(const float* __restrict__ Q,
                                                   const float* __restrict__ KT,
                                                   const float* __restrict__ V,
                                                   float* __restrict__ outV,
                                                   float* __restrict__ outS) {
    const int bx = blockIdx.x;
    const int it = 127 - (bx & 127);        // heavy tiles first
    const int bh = bx >> 7;
    const int b  = bh >> 3;
    const int h  = bh & 7;
    const int i0 = it << 3;
    const int t  = threadIdx.x;
    const int nct  = (i0 + 8 + 255) >> 8;   // 1..4 col-tiles of 256
    const int cend = nct << 8;

    __shared__ float4 smem[2304];           // et0[1152] | et1[1152]; aliased by red
    float4* et0 = smem;
    float4* et1 = smem + 1152;
    float*  red = (float*)smem;             // [16][8][64]
    __shared__ float wsum[4][8];
    __shared__ float sinv[8];

    const float* Qb  = Q  + ((size_t)(b * L_ + i0) * H_ + h) * E_;
    const float* KTb = KT + (size_t)bh * E_ * L_;
    const float* Vb  = V  + ((size_t)b * L_ * H_ + h) * E_;

    float sum_p[8];
#pragma unroll
    for (int r = 0; r < 8; ++r) sum_p[r] = 0.f;
    float e_keep[4][8];

    // ---- Phase 1 ----
#pragma unroll
    for (int ct = 0; ct < 4; ++ct) {
        if (ct >= nct) continue;            // uniform per block
        const int s = (ct << 8) + t;
        float acc[8];
#pragma unroll
        for (int r = 0; r < 8; ++r) acc[r] = 0.f;
        const float* kcol = KTb + s;
#pragma unroll 4
        for (int e4 = 0; e4 < 16; ++e4) {
            const float k0 = kcol[(size_t)((e4 << 2) + 0) * L_];
            const float k1 = kcol[(size_t)((e4 << 2) + 1) * L_];
            const float k2 = kcol[(size_t)((e4 << 2) + 2) * L_];
            const float k3 = kcol[(size_t)((e4 << 2) + 3) * L_];
#pragma unroll
            for (int r = 0; r < 8; ++r) {
                const float4 q4 = *(const float4*)(Qb + r * HE + (e4 << 2));
                acc[r] = fmaf(q4.x, k0, acc[r]);
                acc[r] = fmaf(q4.y, k1, acc[r]);
                acc[r] = fmaf(q4.z, k2, acc[r]);
                acc[r] = fmaf(q4.w, k3, acc[r]);
            }
        }
        float ev[8];
#pragma unroll
        for (int r = 0; r < 8; ++r) {
            ev[r] = (s <= i0 + r) ? __expf(SCALE * acc[r]) : 0.f;
            sum_p[r] += ev[r];
            e_keep[ct][r] = ev[r];
        }
        const int sp = s + (s >> 3);        // pad breaks b128 bank aliasing
        et0[sp] = make_float4(ev[0], ev[1], ev[2], ev[3]);
        et1[sp] = make_float4(ev[4], ev[5], ev[6], ev[7]);
    }

    // ---- Phase 2: row sums ----
#pragma unroll
    for (int r = 0; r < 8; ++r) {
        float v = sum_p[r];
#pragma unroll
        for (int off = 1; off < 64; off <<= 1) v += __shfl_xor(v, off);
        sum_p[r] = v;
    }
    if ((t & 63) == 0) {
#pragma unroll
        for (int r = 0; r < 8; ++r) wsum[t >> 6][r] = sum_p[r];
    }
    __syncthreads();
    if (t < 8) sinv[t] = 1.f / (wsum[0][t] + wsum[1][t] + wsum[2][t] + wsum[3][t]);
    __syncthreads();
    float inv[8];
#pragma unroll
    for (int r = 0; r < 8; ++r) inv[r] = sinv[r];

    // ---- Phase 3: write series ----
    float* Sb = outS + ((size_t)bh * L_ + i0) * L_;
#pragma unroll
    for (int ct = 0; ct < 4; ++ct) {
        if (ct >= nct) continue;
        const int s = (ct << 8) + t;
#pragma unroll
        for (int r = 0; r < 8; ++r) Sb[(size_t)r * L_ + s] = e_keep[ct][r] * inv[r];
    }
    if (cend < 1024) {
        const int z = cend + (t << 2);
        if (z < 1024) {
            const float4 zero = make_float4(0.f, 0.f, 0.f, 0.f);
#pragma unroll
            for (int r = 0; r < 8; ++r) *(float4*)(Sb + (size_t)r * L_ + z) = zero;
        }
    }

    // ---- Phase 4: PV ----
    const int p = t & 15;                   // d-quad
    const int g = t >> 4;                   // s-group (16)
    float va[8][4];
#pragma unroll
    for (int r = 0; r < 8; ++r)
#pragma unroll
        for (int j = 0; j < 4; ++j) va[r][j] = 0.f;
    for (int s = g; s < cend; s += 16) {
        const float4 v4 = *(const float4*)(Vb + (size_t)s * HE + (p << 2));
        const int sp = s + (s >> 3);
        const float4 e0 = et0[sp];
        const float4 e1 = et1[sp];
#pragma unroll
        for (int j = 0; j < 4; ++j) {
            const float vj = j == 0 ? v4.x : j == 1 ? v4.y : j == 2 ? v4.z : v4.w;
            va[0][j] = fmaf(e0.x, vj, va[0][j]);
            va[1][j] = fmaf(e0.y, vj, va[1][j]);
            va[2][j] = fmaf(e0.z, vj, va[2][j]);
            va[3][j] = fmaf(e0.w, vj, va[3][j]);
            va[4][j] = fmaf(e1.x, vj, va[4][j]);
            va[5][j] = fmaf(e1.y, vj, va[5][j]);
            va[6][j] = fmaf(e1.z, vj, va[6][j]);
            va[7][j] = fmaf(e1.w, vj, va[7][j]);
        }
    }
    __syncthreads();                        // done reading et; red aliases it
#pragma unroll
    for (int r = 0; r < 8; ++r)
        *(float4*)&red[(size_t)((g * 8 + r) << 6) + (p << 2)] =
            make_float4(va[r][0], va[r][1], va[r][2], va[r][3]);
    __syncthreads();
    {
        const int rr = t >> 5;              // 0..7
        const int dd = t & 31;              // d-pair index
        float a0 = 0.f, a1 = 0.f;
#pragma unroll
        for (int gg = 0; gg < 16; ++gg) {
            const float2 pr = *(const float2*)&red[(size_t)((gg * 8 + rr) << 6) + (dd << 1)];
            a0 += pr.x; a1 += pr.y;
        }
        const float iv = sinv[rr];
        float2 o; o.x = a0 * iv; o.y = a1 * iv;
        *(float2*)(outV + ((size_t)(b * L_ + i0 + rr) * H_ + h) * E_ + (dd << 1)) = o;
    }
}

extern "C" void kernel_launch(void* const* d_in, const int* in_sizes, int n_in,
                              void* d_out, int out_size, void* d_ws, size_t ws_size,
                              hipStream_t stream) {
    const float* Q     = (const float*)d_in[0];
    const float* K     = (const float*)d_in[1];
    const float* V     = (const float*)d_in[2];
    const float* sigma = (const float*)d_in[3];

    float* out  = (float*)d_out;
    float* outV = out;                                    // (B,L,H,D)   4,194,304
    float* outS = out + (size_t)B_ * L_ * H_ * E_;        // (B,H,L,S)  67,108,864
    float* outP = outS + (size_t)B_ * H_ * L_ * L_;       // (B,L,S)     8,388,608
    float* KT   = outP;                                   // staged KT, overwritten by prior

    ktrans_kernel<<<dim3(B_ * H_ * (L_ / 64)), dim3(256), 0, stream>>>(K, KT);
    attn_kernel<<<dim3(B_ * H_ * (L_ / 8)), dim3(256), 0, stream>>>(Q, KT, V, outV, outS);
    prior_kernel<<<dim3(B_ * (L_ / 4)), dim3(256), 0, stream>>>(sigma, outP);
}

// Round 5
// 400.675 us; speedup vs baseline: 1.9743x; 1.5765x over previous
//
#include <hip/hip_runtime.h>
#include <hip/hip_bf16.h>

#define B_ 8
#define L_ 1024
#define H_ 8
#define E_ 64
// p = 2^(score * 0.125 * log2(e))
#define CL2E 0.18033688f

typedef __attribute__((ext_vector_type(8))) short bf8v;
typedef __attribute__((ext_vector_type(4))) float f32x4;

__device__ __forceinline__ short f2bf(float x) {
    union { float f; unsigned u; } c; c.f = x;
    const unsigned r = (c.u + 0x7fffu + ((c.u >> 16) & 1u)) >> 16;
    return (short)r;
}

// ---------------------------------------------------------------------------
// K -> bf16, layout [bh][s][e].  4096 blocks x 256 thr (1 float4 each).
// ---------------------------------------------------------------------------
__global__ __launch_bounds__(256) void kconv_kernel(const float* __restrict__ K,
                                                    short* __restrict__ Kb) {
    const int g = blockIdx.x * 256 + threadIdx.x;      // float4 index == linear/4
    const float4 v = *((const float4*)K + g);
    const int e4 = g & 15, h = (g >> 4) & 7, l = (g >> 7) & 1023, b = g >> 17;
    short4 o; o.x = f2bf(v.x); o.y = f2bf(v.y); o.z = f2bf(v.z); o.w = f2bf(v.w);
    *(short4*)(Kb + (((size_t)(b * 8 + h)) << 16) + l * 64 + (e4 << 2)) = o;
}

// ---------------------------------------------------------------------------
// V -> bf16 transposed, layout [bh][d][s].  1024 blocks x 256 thr.
// ---------------------------------------------------------------------------
__global__ __launch_bounds__(256) void vtrans_kernel(const float* __restrict__ V,
                                                     short* __restrict__ VT) {
    const int bx = blockIdx.x;
    const int bh = bx >> 4; const int l0 = (bx & 15) << 6;
    const int b = bh >> 3, h = bh & 7;
    const int t = threadIdx.x;
    __shared__ float lds[64][65];
    {
        const int r = t >> 2, cq = t & 3;
        const float* src = V + ((size_t)((b * 1024 + l0 + r) * 8) + h) * 64 + (cq << 4);
#pragma unroll
        for (int j = 0; j < 4; ++j) {
            const float4 v = *(const float4*)(src + (j << 2));
            const int d = (cq << 4) + (j << 2);
            lds[r][d] = v.x; lds[r][d + 1] = v.y; lds[r][d + 2] = v.z; lds[r][d + 3] = v.w;
        }
    }
    __syncthreads();
    {
        const int d = t >> 2, lq = t & 3;
        short tmp[16];
#pragma unroll
        for (int k = 0; k < 16; ++k) tmp[k] = f2bf(lds[(lq << 4) + k][d]);
        short* dst = VT + ((size_t)bh << 16) + d * 1024 + l0 + (lq << 4);
        *(bf8v*)dst = *(bf8v*)tmp;
        *(bf8v*)(dst + 8) = *(bf8v*)(tmp + 8);
    }
}

// ---------------------------------------------------------------------------
// prior: 2048 blocks (b, 4-row group) x 256 thr; all-register, native rcp/exp2.
// ---------------------------------------------------------------------------
__global__ __launch_bounds__(256) void prior_kernel(const float* __restrict__ sigma,
                                                    float* __restrict__ outP) {
    const int bx = blockIdx.x;
    const int b  = bx >> 8;
    const int i0 = (bx & 255) << 2;
    const int t  = threadIdx.x;
    const int s0 = t << 2;

    __shared__ float wred[4][4];
    __shared__ float sinv[4];

    const float* sb = sigma + (size_t)b * H_ * L_;
    float wv[8][4];
#pragma unroll
    for (int h = 0; h < 8; ++h) {
        const float4 sg = *(const float4*)(sb + h * L_ + s0);
        wv[h][0] = -1.4426950408889634f * __builtin_amdgcn_rcpf(sg.x);
        wv[h][1] = -1.4426950408889634f * __builtin_amdgcn_rcpf(sg.y);
        wv[h][2] = -1.4426950408889634f * __builtin_amdgcn_rcpf(sg.z);
        wv[h][3] = -1.4426950408889634f * __builtin_amdgcn_rcpf(sg.w);
    }
    float acc[4][4];
#pragma unroll
    for (int row = 0; row < 4; ++row)
#pragma unroll
        for (int j = 0; j < 4; ++j) acc[row][j] = 0.f;
#pragma unroll
    for (int h = 0; h < 8; ++h)
#pragma unroll
        for (int row = 0; row < 4; ++row)
#pragma unroll
            for (int j = 0; j < 4; ++j) {
                int di = (i0 + row) - (s0 + j);
                const float dist = (float)(di < 0 ? -di : di);
                acc[row][j] += __builtin_amdgcn_exp2f(dist * wv[h][j]);
            }
    float tsum[4];
#pragma unroll
    for (int row = 0; row < 4; ++row) {
        float v = acc[row][0] + acc[row][1] + acc[row][2] + acc[row][3];
#pragma unroll
        for (int off = 1; off < 64; off <<= 1) v += __shfl_xor(v, off);
        tsum[row] = v;
    }
    if ((t & 63) == 0) {
#pragma unroll
        for (int row = 0; row < 4; ++row) wred[t >> 6][row] = tsum[row];
    }
    __syncthreads();
    if (t < 4) sinv[t] = 1.f / (wred[0][t] + wred[1][t] + wred[2][t] + wred[3][t]);
    __syncthreads();
#pragma unroll
    for (int row = 0; row < 4; ++row) {
        const float iv = sinv[row];
        float4 o;
        o.x = acc[row][0] * iv; o.y = acc[row][1] * iv;
        o.z = acc[row][2] * iv; o.w = acc[row][3] * iv;
        *(float4*)(outP + (size_t)(b * L_ + i0 + row) * L_ + s0) = o;
    }
}

// ---------------------------------------------------------------------------
// MFMA attention: 1024 blocks = (qtile 16, heavy first) x (bh 64); 4 waves.
// Pass A: QK^T (mfma 16x16x32 bf16) + exp2 -> row sums (in-lane reduction).
// Pass B: recompute QK^T, write normalized P (f32) to outS, P->bf16 through
//         a per-wave XOR-swizzled LDS slab, PV mfma accumulate, write outV.
// ---------------------------------------------------------------------------
__global__ __launch_bounds__(256, 4) void attn_kernel(const float* __restrict__ Q,
                                                      const short* __restrict__ Kbf,
                                                      const short* __restrict__ VTbf,
                                                      float* __restrict__ outV,
                                                      float* __restrict__ outS) {
    const int bx = blockIdx.x;
    const int qt = 15 - (bx >> 6);          // heavy tiles dispatch first
    const int bh = bx & 63;
    const int b = bh >> 3, h = bh & 7;
    const int q0 = qt << 6;
    const int t = threadIdx.x;
    const int lane = t & 63, w = t >> 6;
    const int l15 = lane & 15, l4 = lane >> 4;
    const int nch = qt + 1;

    __shared__ __align__(16) short Klds[4096];   // [s 64][e 64], swizzled
    __shared__ __align__(16) short Vlds[4096];   // [d 64][s 64], swizzled
    __shared__ __align__(16) short Plds[4096];   // 4 x [q 16][s 64], swizzled

    const short* Kb = Kbf + ((size_t)bh << 16);
    const short* Vb = VTbf + ((size_t)bh << 16);

    // staging lane geometry: 8 rows x 8 slots of 16B per wave-instruction
    const int srow = lane >> 3;
    const int sslot = lane & 7;
    const int pslot = sslot ^ srow;              // XOR swizzle (row&7)

    // Q A-fragments: row = lane&15, k = (lane>>4)*8 + j
    bf8v aq0, aq1;
    {
        const float* Qrow = Q + ((size_t)((b * 1024 + q0 + 16 * w + l15) * 8) + h) * 64 + l4 * 8;
#pragma unroll
        for (int j = 0; j < 8; ++j) aq0[j] = f2bf(Qrow[j]);
#pragma unroll
        for (int j = 0; j < 8; ++j) aq1[j] = f2bf(Qrow[32 + j]);
    }

    float* outSb = outS + ((size_t)bh << 20) + (size_t)q0 * 1024;

    // zero-fill cols beyond the causal chunks
    {
        const int cend = nch << 6;
        const float4 z4 = make_float4(0.f, 0.f, 0.f, 0.f);
        for (int col = cend + (lane << 2); col < 1024; col += 256) {
            float* rp = outSb + (size_t)(16 * w) * 1024 + col;
#pragma unroll
            for (int rr = 0; rr < 16; ++rr) *(float4*)(rp + (size_t)rr * 1024) = z4;
        }
    }

    // ---------------- Pass A: row sums ----------------
    float sum4[4] = {0.f, 0.f, 0.f, 0.f};
    for (int c = 0; c < nch; ++c) {
        const int s0 = c << 6;
        __syncthreads();
#pragma unroll
        for (int p = 0; p < 2; ++p) {
            const int krow = 16 * w + 8 * p + srow;
            const bf8v kv = *(const bf8v*)(Kb + (size_t)(s0 + krow) * 64 + sslot * 8);
            *(bf8v*)((char*)Klds + krow * 128 + (pslot << 4)) = kv;
        }
        __syncthreads();
        const bool diag = (c == qt);
#pragma unroll
        for (int cb = 0; cb < 4; ++cb) {
            const int krow = (cb << 4) + l15;
            const char* kp = (char*)Klds + krow * 128;
            const int sw = (krow & 7) << 4;
            const bf8v b0 = *(const bf8v*)(kp + ((l4 << 4) ^ sw));
            const bf8v b1 = *(const bf8v*)(kp + ((64 + (l4 << 4)) ^ sw));
            f32x4 acc = {0.f, 0.f, 0.f, 0.f};
            acc = __builtin_amdgcn_mfma_f32_16x16x32_bf16(aq0, b0, acc, 0, 0, 0);
            acc = __builtin_amdgcn_mfma_f32_16x16x32_bf16(aq1, b1, acc, 0, 0, 0);
#pragma unroll
            for (int r = 0; r < 4; ++r) {
                float e = __builtin_amdgcn_exp2f(acc[r] * CL2E);
                if (diag && ((cb << 4) + l15 > 16 * w + (l4 << 2) + r)) e = 0.f;
                sum4[r] += e;
            }
        }
    }
#pragma unroll
    for (int r = 0; r < 4; ++r) {
        float v = sum4[r];
        v += __shfl_xor(v, 1); v += __shfl_xor(v, 2);
        v += __shfl_xor(v, 4); v += __shfl_xor(v, 8);
        sum4[r] = v;
    }
    float inv4[4];
#pragma unroll
    for (int r = 0; r < 4; ++r) inv4[r] = __builtin_amdgcn_rcpf(sum4[r]);

    // ---------------- Pass B: P writes + PV ----------------
    f32x4 oacc[4];
#pragma unroll
    for (int db = 0; db < 4; ++db) oacc[db] = (f32x4){0.f, 0.f, 0.f, 0.f};

    short* Pw = Plds + (w << 10);
    float* sbase = outSb + (size_t)(16 * w + (l4 << 2)) * 1024 + l15;

    for (int c = 0; c < nch; ++c) {
        const int s0 = c << 6;
        __syncthreads();
#pragma unroll
        for (int p = 0; p < 2; ++p) {
            const int krow = 16 * w + 8 * p + srow;
            const bf8v kv = *(const bf8v*)(Kb + (size_t)(s0 + krow) * 64 + sslot * 8);
            *(bf8v*)((char*)Klds + krow * 128 + (pslot << 4)) = kv;
            const bf8v vv = *(const bf8v*)(Vb + (size_t)krow * 1024 + s0 + sslot * 8);
            *(bf8v*)((char*)Vlds + krow * 128 + (pslot << 4)) = vv;
        }
        __syncthreads();
        const bool diag = (c == qt);
#pragma unroll
        for (int cb = 0; cb < 4; ++cb) {
            const int krow = (cb << 4) + l15;
            const char* kp = (char*)Klds + krow * 128;
            const int sw = (krow & 7) << 4;
            const bf8v b0 = *(const bf8v*)(kp + ((l4 << 4) ^ sw));
            const bf8v b1 = *(const bf8v*)(kp + ((64 + (l4 << 4)) ^ sw));
            f32x4 acc = {0.f, 0.f, 0.f, 0.f};
            acc = __builtin_amdgcn_mfma_f32_16x16x32_bf16(aq0, b0, acc, 0, 0, 0);
            acc = __builtin_amdgcn_mfma_f32_16x16x32_bf16(aq1, b1, acc, 0, 0, 0);
#pragma unroll
            for (int r = 0; r < 4; ++r) {
                float e = __builtin_amdgcn_exp2f(acc[r] * CL2E);
                if (diag && ((cb << 4) + l15 > 16 * w + (l4 << 2) + r)) e = 0.f;
                const float pv = e * inv4[r];
                sbase[(size_t)r * 1024 + s0 + (cb << 4)] = pv;
                const int row = (l4 << 2) + r;
                const int byte = row * 128 +
                                 ((((cb << 1) + (l15 >> 3)) ^ (row & 7)) << 4) +
                                 ((l15 & 7) << 1);
                *(short*)((char*)Pw + byte) = f2bf(pv);
            }
        }
        // PV: A = P (row=q local=lane&15), B = V^T rows
        const int swp = (l15 & 7) << 4;
        const bf8v p0 = *(const bf8v*)((char*)Pw + l15 * 128 + ((l4 << 4) ^ swp));
        const bf8v p1 = *(const bf8v*)((char*)Pw + l15 * 128 + (((4 + l4) << 4) ^ swp));
#pragma unroll
        for (int db = 0; db < 4; ++db) {
            const int vrow = (db << 4) + l15;
            const char* vp = (char*)Vlds + vrow * 128;
            const int swv = (vrow & 7) << 4;
            const bf8v v0 = *(const bf8v*)(vp + ((l4 << 4) ^ swv));
            const bf8v v1 = *(const bf8v*)(vp + (((4 + l4) << 4) ^ swv));
            oacc[db] = __builtin_amdgcn_mfma_f32_16x16x32_bf16(p0, v0, oacc[db], 0, 0, 0);
            oacc[db] = __builtin_amdgcn_mfma_f32_16x16x32_bf16(p1, v1, oacc[db], 0, 0, 0);
        }
    }

#pragma unroll
    for (int db = 0; db < 4; ++db)
#pragma unroll
        for (int r = 0; r < 4; ++r)
            outV[((size_t)((b * 1024 + q0 + 16 * w + (l4 << 2) + r) * 8) + h) * 64 +
                 (db << 4) + l15] = oacc[db][r];
}

extern "C" void kernel_launch(void* const* d_in, const int* in_sizes, int n_in,
                              void* d_out, int out_size, void* d_ws, size_t ws_size,
                              hipStream_t stream) {
    const float* Q     = (const float*)d_in[0];
    const float* K     = (const float*)d_in[1];
    const float* V     = (const float*)d_in[2];
    const float* sigma = (const float*)d_in[3];

    float* out  = (float*)d_out;
    float* outV = out;                                    // (B,L,H,D)   4,194,304
    float* outS = out + (size_t)B_ * L_ * H_ * E_;        // (B,H,L,S)  67,108,864
    float* outP = outS + (size_t)B_ * H_ * L_ * L_;       // (B,L,S)     8,388,608

    short* Kbf = (short*)outP;                            // 8.39 MB staging
    short* VTb = Kbf + ((size_t)64 << 16);                // 8.39 MB staging

    kconv_kernel<<<dim3(4096), dim3(256), 0, stream>>>(K, Kbf);
    vtrans_kernel<<<dim3(1024), dim3(256), 0, stream>>>(V, VTb);
    attn_kernel<<<dim3(1024), dim3(256), 0, stream>>>(Q, Kbf, VTb, outV, outS);
    prior_kernel<<<dim3(B_ * (L_ / 4)), dim3(256), 0, stream>>>(sigma, outP);
}